// Round 6
// baseline (11159.509 us; speedup 1.0000x reference)
//
#include <hip/hip_runtime.h>

// Problem sizes
#define SEQ   512
#define NB    32
#define NH    512
#define BH    16384       // NB*NH
#define EPSF  1e-7f
#define NWG   64          // workgroups in persistent recurrent kernel

// d_out offsets (float elements): out(S,B,O), h_f(1,B,H), c_f(1,B,H), mem_f(513,B,H)
#define HF_OFF  8388608
#define CF_OFF  8404992
#define MEM_OFF 8421376

// ws offsets (bytes)
#define X0_OFF   0ul          // u16 [512][32][512]  bf16 hi of x
#define X1_OFF   16777216ul   // u16 mid of x
#define WI0_OFF  33554432ul   // u16 [2048][512] w_ih hi   (dead after xgemm; bar2 reuses it)
#define WI1_OFF  35651584ul   // u16 mid
#define HH_OFF   37748736ul   // u16 [513][64g][32b][8c]  h hi  (slot0=h0, slot t+1=h_out_t)
#define HMF_OFF  54558720ul   // u16 [513][64g][32b][8c]  h mid
#define MSEQ_OFF 71368704ul   // u16 [512][32][512]  bf16(m_t)
#define FCW_OFF  88145920ul   // u16 [512][1024]     bf16(fc_w)
#define S2P_OFF  89194496ul   // f32 [513][64g][32b] per-WG score partials (write-once slots)
#define BAR_OFF  93396992ul   // u32 [64][32]        init-barrier slots, 128-B padded
#define GX_OFF   93405184ul   // f32 [512*32][2048]  precomputed x@w_ih^T + b_ih + b_hh
#define BAR2_OFF WI0_OFF      // u32 [64c][256p] flag matrix: p = producer wg*4 + wave

typedef __attribute__((ext_vector_type(8))) short bf16x8;
typedef __attribute__((ext_vector_type(4))) float f32x4;
typedef __attribute__((ext_vector_type(4))) int   i32x4;

#define AL(p) __hip_atomic_load((p), __ATOMIC_RELAXED, __HIP_MEMORY_SCOPE_AGENT)
#define AS(p,v) __hip_atomic_store((p), (v), __ATOMIC_RELAXED, __HIP_MEMORY_SCOPE_AGENT)

__device__ __forceinline__ unsigned short f2bf(float f){
  unsigned u = __float_as_uint(f);
  unsigned r = (u + 0x7fffu + ((u >> 16) & 1u)) >> 16;   // RNE
  return (unsigned short)r;
}
__device__ __forceinline__ float bf2f(unsigned short h){
  return __uint_as_float(((unsigned)h) << 16);
}
__device__ __forceinline__ float sigmf(float x){ return 1.f/(1.f + __expf(-x)); }
__device__ __forceinline__ float tanhff(float x){
  x = fminf(20.f, fmaxf(-20.f, x));
  float e = __expf(-2.f*x);
  return (1.f - e)/(1.f + e);
}

// stores bypassing L1/L2 (write-through to LLC), line-contention-free when WG-exclusive
__device__ __forceinline__ void store16_cc(void* p, i32x4 v){
  asm volatile("global_store_dwordx4 %0, %1, off sc0 sc1" :: "v"(p), "v"(v) : "memory");
}
__device__ __forceinline__ void store4_cc(void* p, unsigned v){
  asm volatile("global_store_dword %0, %1, off sc0 sc1" :: "v"(p), "v"(v) : "memory");
}

// ---------------- phase 0: 2-way bf16 splits + init (zeroes init-barrier every launch)
__global__ void phase0(const float* __restrict__ x, const float* __restrict__ h0,
                       const float* __restrict__ mem0, const float* __restrict__ fcw,
                       const float* __restrict__ wih,
                       unsigned short* __restrict__ x0, unsigned short* __restrict__ x1,
                       unsigned short* __restrict__ wi0, unsigned short* __restrict__ wi1,
                       unsigned short* __restrict__ hh, unsigned short* __restrict__ hmf,
                       unsigned short* __restrict__ fcwb,
                       float* __restrict__ mem_row0, unsigned* __restrict__ bar){
  long i = (long)blockIdx.x * blockDim.x + threadIdx.x;
  if (i < (long)SEQ*BH){
    float v = x[i];
    unsigned short a = f2bf(v);
    x0[i]=a; x1[i]=f2bf(v - bf2f(a));
  }
  if (i < 2048*512){
    float v = wih[i];
    unsigned short a = f2bf(v);
    wi0[i]=a; wi1[i]=f2bf(v - bf2f(a));
  }
  if (i < 512*1024) fcwb[i] = f2bf(fcw[i]);
  if (i < BH){
    float h = h0[i];
    unsigned short a = f2bf(h);
    int b = (int)(i >> 9), col = (int)(i & 511);
    long d = (long)(col>>3)*256 + b*8 + (col&7);     // [g][b][c] layout, slot 0
    hh[d]=a; hmf[d]=f2bf(h - bf2f(a));
    mem_row0[i] = mem0[i];
  }
  if (i < 2048) bar[i] = 0u;                          // 64 slots x 128 B (init barrier)
}

// ---------------- phase 1: G_x = x @ w_ih^T + b_ih + b_hh  (3-term split MFMA)
__launch_bounds__(256)
__global__ void xgemm(const unsigned short* __restrict__ x0, const unsigned short* __restrict__ x1,
                      const unsigned short* __restrict__ wi0, const unsigned short* __restrict__ wi1,
                      const float* __restrict__ bih, const float* __restrict__ bhh,
                      float* __restrict__ gx){
  const int tid = threadIdx.x;
  const int wave = tid >> 6, lane = tid & 63, quad = lane >> 4, ln = lane & 15;
  const int rowb = blockIdx.x*64 + wave*16;
  const int colb = blockIdx.y*64;
  const long aoff = (long)(rowb + ln)*512 + quad*8;
  f32x4 acc[4] = {{0,0,0,0},{0,0,0,0},{0,0,0,0},{0,0,0,0}};
  #pragma unroll 4
  for (int ki = 0; ki < 16; ++ki){
    bf16x8 a0 = *(const bf16x8*)(x0 + aoff + ki*32);
    bf16x8 a1 = *(const bf16x8*)(x1 + aoff + ki*32);
    #pragma unroll
    for (int n = 0; n < 4; ++n){
      long bo = (long)(colb + n*16 + ln)*512 + quad*8 + ki*32;
      bf16x8 b0 = *(const bf16x8*)(wi0 + bo);
      bf16x8 b1 = *(const bf16x8*)(wi1 + bo);
      acc[n] = __builtin_amdgcn_mfma_f32_16x16x32_bf16(a0, b0, acc[n], 0,0,0);
      acc[n] = __builtin_amdgcn_mfma_f32_16x16x32_bf16(a0, b1, acc[n], 0,0,0);
      acc[n] = __builtin_amdgcn_mfma_f32_16x16x32_bf16(a1, b0, acc[n], 0,0,0);
    }
  }
  #pragma unroll
  for (int n = 0; n < 4; ++n){
    int col = colb + n*16 + ln;
    float bias = bih[col] + bhh[col];
    #pragma unroll
    for (int rr = 0; rr < 4; ++rr){
      int row = rowb + quad*4 + rr;
      gx[(long)row*2048 + col] = acc[n][rr] + bias;
    }
  }
}

// ---------------- phase 2: persistent recurrent kernel: 64 WGs x 320 threads
// Distributed barrier: per-producer-WAVE flags (bar2[consumer][wg*4+wave]).
// Each MFMA wave publishes its OWN 8 batch-rows right after elementwise (shfl pack,
// no cross-wave LDS), then stores its flag; consumers self-release by polling their
// own contiguous flag row. Only ONE intra-WG barrier (sync_A) per step; gates/wt/repl
// LDS double-buffered by step parity (max skew 1 step, bounded by flag deps).
__launch_bounds__(320, 1)
__global__ void recurrent(unsigned short* __restrict__ hh,
                          unsigned short* __restrict__ hmf,
                          unsigned short* __restrict__ mseq,
                          float* __restrict__ s2p,
                          unsigned* __restrict__ bar,
                          unsigned* __restrict__ bar2,
                          float* __restrict__ dout,
                          const float* __restrict__ gx,
                          const float* __restrict__ whh,
                          const float* __restrict__ wt,
                          const float* __restrict__ c0){
  const int g    = blockIdx.x;           // WG owns hidden cols [g*8, g*8+8), all 4 gates
  const int tid  = threadIdx.x;
  const int wave = tid >> 6, lane = tid & 63, quad = lane >> 4, ln = lane & 15;
  const int mtile = wave & 1, ntile = wave >> 1;   // 32x32 tile = 2x2 of 16x16 per wave

  __shared__ float gates_lds[2][32*33];  // [parity][b][c], padded
  __shared__ float wt_lds[2][32*5];
  __shared__ int   repl_lds[2][32];

  // zero own flag row (256 producer-wave flags); ordered by init rendezvous below
  if (tid < 256) AS(&bar2[(long)g*256 + tid], 0u);

  // w_hh 2-split fragments in registers (hi+mid, 3-term scheme) — MFMA waves only
  bf16x8 fW0[16], fW1[16];
  if (wave < 4){
    int cl   = ntile*16 + ln;            // local col 0..31; c = gate*8 + jloc
    int gate = cl >> 3, jl = cl & 7;
    long grow = (long)(gate*NH + g*8 + jl);
    const float* wh = whh + grow*NH;
    #pragma unroll
    for (int ki = 0; ki < 16; ++ki){
      int k0 = ki*32 + quad*8;
      bf16x8 a, b;
      #pragma unroll
      for (int e = 0; e < 8; ++e){
        float vh = wh[k0+e];
        unsigned short w0 = f2bf(vh);
        a[e] = (short)w0; b[e] = (short)f2bf(vh - bf2f(w0));
      }
      fW0[ki]=a; fW1[ki]=b;
    }
  }

  // elementwise ownership: thread <-> (b, jloc), threads 0..255 only
  const int b_  = tid >> 3, jl_ = tid & 7;
  const int jg_ = g*8 + jl_;
  const float wt2 = wt[NH + jg_];        // memory half of w_t (h half cancels)
  float* memf = dout + MEM_OFF;
  float creg = 0.f, m0v = 0.f;
  if (tid < 256){
    creg = c0[b_*NH + jg_];
    m0v  = memf[b_*NH + jg_];            // entry 0 = mem0
  }
  // register-resident top-5 values (va_l = mem value of slot l's index, own column)
  float va0 = 0.f, va1 = 0.f, va2 = 0.f, va3 = 0.f, va4 = 0.f;
  float hoprev = m0v;                    // value of entry index t, at step t

  // s2 partial for entry 0 (= mem0), layout [513][64][32]
  if (tid < 256){
    float v = tanhff(m0v) * wt2;
    v += __shfl_xor(v, 1); v += __shfl_xor(v, 2); v += __shfl_xor(v, 4);
    if (jl_ == 0)
      AS((unsigned*)(s2p + g*32 + b_), __float_as_uint(v));
  }

  // gx prefetch for t=0
  float gxi = 0.f, gxf = 0.f, gxg = 0.f, gxo = 0.f;
  if (tid < 256){
    const float* gxr0 = gx + (long)b_*2048 + jg_;
    gxi = gxr0[0]; gxf = gxr0[512]; gxg = gxr0[1024]; gxo = gxr0[1536];
  }

  // replicated incremental top-5 (wave4 lanes 0..31, lane = batch)
  float tv0=-3e38f,tv1=-3e38f,tv2=-3e38f,tv3=-3e38f,tv4=-3e38f;

  // ---- init rendezvous (old bar array): orders bar2 zeroing + s2p slot0 globally
  __syncthreads();                       // drains vmcnt: zeros + s2p[0] landed
  if (tid == 0) AS(&bar[g*32], 1u);
  if (tid < 64){
    while (true){
      unsigned v = AL(&bar[tid*32]);
      if (__all((int)(v >= 1u))) break;
    }
  }
  __syncthreads();

  const int arow = mtile*16 + ln;        // A-frag row (batch)

  #pragma unroll 1
  for (int t = 0; t < SEQ; ++t){
    const int par = t & 1;
    // --- distributed detect: poll own flag row until all 256 producer waves >= t
    {
      const unsigned tt = (unsigned)t;
      const unsigned* fr = bar2 + (long)g*256 + lane*4;
      while (true){
        unsigned f0 = AL(fr+0), f1 = AL(fr+1), f2 = AL(fr+2), f3 = AL(fr+3);
        bool ok = (f0 >= tt) & (f1 >= tt) & (f2 >= tt) & (f3 >= tt);
        if (__all((int)ok)) break;
      }
    }

    if (tid >= 256){
      // --- wave4: s2p slot t, finalize score, top-5, weights + replaced slot
      const int l4 = tid - 256;
      if (l4 < 32){
        const float* sp = s2p + (long)t*2048 + l4;
        float s0=0.f,s1=0.f,s2v=0.f,s3=0.f;
        #pragma unroll
        for (int q = 0; q < 64; q += 4){
          s0  += sp[(q  )*32];
          s1  += sp[(q+1)*32];
          s2v += sp[(q+2)*32];
          s3  += sp[(q+3)*32];
        }
        float s = (s0+s1) + (s2v+s3);    // fixed order → bit-identical across WGs
        int repl = -1;
        if (t < 5){
          repl = t;
          if      (t==0) tv0=s;
          else if (t==1) tv1=s;
          else if (t==2) tv2=s;
          else if (t==3) tv3=s;
          else           tv4=s;
        } else {
          float mn = fminf(fminf(fminf(tv0,tv1),fminf(tv2,tv3)),tv4);
          if (s > mn){
            if      (tv0==mn){tv0=s;repl=0;}
            else if (tv1==mn){tv1=s;repl=1;}
            else if (tv2==mn){tv2=s;repl=2;}
            else if (tv3==mn){tv3=s;repl=3;}
            else             {tv4=s;repl=4;}
          }
        }
        int cnt = (t+1 < 5) ? (t+1) : 5;
        float mn = tv0;
        if (cnt>1) mn = fminf(mn, tv1);
        if (cnt>2) mn = fminf(mn, tv2);
        if (cnt>3) mn = fminf(mn, tv3);
        if (cnt>4) mn = fminf(mn, tv4);
        float thr = mn + EPSF;           // kth/min + eps; h-term cancels
        float w0 =            fmaxf(tv0-thr,0.f);
        float w1 = (cnt>1) ? fmaxf(tv1-thr,0.f) : 0.f;
        float w2 = (cnt>2) ? fmaxf(tv2-thr,0.f) : 0.f;
        float w3 = (cnt>3) ? fmaxf(tv3-thr,0.f) : 0.f;
        float w4 = (cnt>4) ? fmaxf(tv4-thr,0.f) : 0.f;
        float inv = 1.f/((w0+w1+w2+w3+w4) + EPSF);
        wt_lds[par][l4*5+0]=w0*inv;
        wt_lds[par][l4*5+1]=w1*inv;
        wt_lds[par][l4*5+2]=w2*inv;
        wt_lds[par][l4*5+3]=w3*inv;
        wt_lds[par][l4*5+4]=w4*inv;
        repl_lds[par][l4]=repl;
      }
    } else {
      // --- waves 0-3: gates tile h_t @ w_hh^T, 3-term split MFMA (baseline codegen)
      const unsigned short* p0 = hh  + (long)t*BH + quad*256 + arow*8;
      const unsigned short* p1 = hmf + (long)t*BH + quad*256 + arow*8;
      f32x4 acc0 = {0.f,0.f,0.f,0.f}, acc1 = {0.f,0.f,0.f,0.f};
      #pragma unroll
      for (int ki = 0; ki < 16; ++ki){
        bf16x8 aH = *(const bf16x8*)(p0 + ki*1024);
        bf16x8 aM = *(const bf16x8*)(p1 + ki*1024);
        acc0 = __builtin_amdgcn_mfma_f32_16x16x32_bf16(aH, fW0[ki], acc0, 0,0,0);
        acc1 = __builtin_amdgcn_mfma_f32_16x16x32_bf16(aH, fW1[ki], acc1, 0,0,0);
        if (ki & 1) acc1 = __builtin_amdgcn_mfma_f32_16x16x32_bf16(aM, fW0[ki], acc1, 0,0,0);
        else        acc0 = __builtin_amdgcn_mfma_f32_16x16x32_bf16(aM, fW0[ki], acc0, 0,0,0);
      }
      #pragma unroll
      for (int r = 0; r < 4; ++r){
        int brow = mtile*16 + quad*4 + r;  // C/D: row=quad*4+reg, col=lane&15
        gates_lds[par][brow*33 + ntile*16 + ln] = acc0[r] + acc1[r];
      }
    }
    __syncthreads();                     // sync_A: gates + wt + repl ready (ONLY barrier)

    if (tid < 256){
      // --- LSTM elementwise (gates = G_x[t] + h-path) + register top-5 combine
      float g0 = gates_lds[par][b_*33 + jl_     ] + gxi;   // i
      float g1 = gates_lds[par][b_*33 +  8 + jl_] + gxf;   // f
      float g2 = gates_lds[par][b_*33 + 16 + jl_] + gxg;   // g
      float g3 = gates_lds[par][b_*33 + 24 + jl_] + gxo;   // o
      float ig = sigmf(g0), fg = sigmf(g1), gg = tanhff(g2), og = sigmf(g3);
      creg = fg*creg + ig*gg;
      float hn = og * tanhff(creg);

      int rp = repl_lds[par][b_];
      va0 = (rp==0) ? hoprev : va0;
      va1 = (rp==1) ? hoprev : va1;
      va2 = (rp==2) ? hoprev : va2;
      va3 = (rp==3) ? hoprev : va3;
      va4 = (rp==4) ? hoprev : va4;
      float mt = wt_lds[par][b_*5+0]*va0 + wt_lds[par][b_*5+1]*va1
               + wt_lds[par][b_*5+2]*va2 + wt_lds[par][b_*5+3]*va3
               + wt_lds[par][b_*5+4]*va4;
      float ho = hn + mt;

      // s2 partial of the appended entry (t+1): all lanes get the 8-group sum
      float sv = tanhff(ho) * wt2;
      sv += __shfl_xor(sv, 1); sv += __shfl_xor(sv, 2); sv += __shfl_xor(sv, 4);

      // --- per-wave publish: shfl-pack own 8 batch-rows, sc stores, ack, flag
      unsigned packed = (unsigned)f2bf(ho);
      {
        unsigned short h1s = f2bf(ho - bf2f((unsigned short)packed));
        packed |= ((unsigned)h1s) << 16;
      }
      unsigned q0 = __shfl(packed, lane*8+0), q1 = __shfl(packed, lane*8+1);
      unsigned q2 = __shfl(packed, lane*8+2), q3 = __shfl(packed, lane*8+3);
      unsigned q4 = __shfl(packed, lane*8+4), q5 = __shfl(packed, lane*8+5);
      unsigned q6 = __shfl(packed, lane*8+6), q7 = __shfl(packed, lane*8+7);
      if (lane < 8){
        i32x4 hi, mi;
        hi[0] = (int)((q0 & 0xffffu) | (q1 << 16));
        hi[1] = (int)((q2 & 0xffffu) | (q3 << 16));
        hi[2] = (int)((q4 & 0xffffu) | (q5 << 16));
        hi[3] = (int)((q6 & 0xffffu) | (q7 << 16));
        mi[0] = (int)((q0 >> 16) | (q1 & 0xffff0000u));
        mi[1] = (int)((q2 >> 16) | (q3 & 0xffff0000u));
        mi[2] = (int)((q4 >> 16) | (q5 & 0xffff0000u));
        mi[3] = (int)((q6 >> 16) | (q7 & 0xffff0000u));
        long d = (long)(t+1)*BH + g*256 + (wave*8 + lane)*8;   // elements
        store16_cc(hh  + d, hi);
        store16_cc(hmf + d, mi);
      }
      if (jl_ == 0)
        store4_cc(s2p + (long)(t+1)*2048 + g*32 + b_, __float_as_uint(sv));
      asm volatile("s_waitcnt vmcnt(0)" ::: "memory");   // publish acked at LLC
      AS(&bar2[(long)lane*256 + g*4 + wave], (unsigned)(t+1));  // flag all consumers

      // --- non-critical stores + next-step gx prefetch (overlap with next poll)
      long eoff = (long)b_*NH + jg_;
      memf[(long)(t+1)*BH + eoff] = ho;               // mem append == h_seq (own)
      mseq[(long)t*BH + eoff] = f2bf(mt);             // consumed by outgemm
      if (t == SEQ-1) dout[HF_OFF + eoff] = ho;       // h_f
      hoprev = ho;
      int tn = (t+1 < SEQ) ? t+1 : t;
      const float* gxr = gx + ((long)tn*32 + b_)*2048 + jg_;
      gxi = gxr[0]; gxf = gxr[512]; gxg = gxr[1024]; gxo = gxr[1536];
    }
    // no sync_B / sync_C: consumers self-release via flags
  }
  if (tid < 256)
    dout[CF_OFF + (long)b_*NH + jg_] = creg;          // c_f
}

// ---------------- phase 3: out = [h_seq; m_seq] @ fc_w^T + fc_b   (M=16384, N=512, K=1024)
__launch_bounds__(256)
__global__ void outgemm(const unsigned short* __restrict__ hh,
                        const unsigned short* __restrict__ mseq,
                        const unsigned short* __restrict__ fcwb,
                        const float* __restrict__ fcb,
                        float* __restrict__ out){
  const int tid = threadIdx.x;
  const int wave = tid >> 6, lane = tid & 63, quad = lane >> 4, ln = lane & 15;
  const int wgM = blockIdx.x;            // 256 tiles of 64 rows
  const int wgN = blockIdx.y;            // 8 tiles of 64 cols
  const int r = wgM*64 + wave*16 + ln;   // row (s*32+b); 16-row tiles never straddle s
  const int s = r >> 5, b = r & 31;
  // h_seq[s] = hh slot s+1, layout [g][b][8c]
  const unsigned short* pa_h = hh   + (long)(s+1)*BH + quad*256 + b*8;
  const unsigned short* pa_m = mseq + (long)s*BH     + (long)b*NH + quad*8;
  const unsigned short* pb   = fcwb + (long)(wgN*64 + ln)*1024 + quad*8;
  f32x4 accs[4] = {{0,0,0,0},{0,0,0,0},{0,0,0,0},{0,0,0,0}};
  #pragma unroll 4
  for (int ki = 0; ki < 16; ++ki){       // h half (k < 512)
    bf16x8 a = *(const bf16x8*)(pa_h + ki*1024);
    #pragma unroll
    for (int n = 0; n < 4; ++n){
      bf16x8 bb = *(const bf16x8*)(pb + (long)n*16*1024 + ki*32);
      accs[n] = __builtin_amdgcn_mfma_f32_16x16x32_bf16(a, bb, accs[n], 0,0,0);
    }
  }
  #pragma unroll 4
  for (int ki = 0; ki < 16; ++ki){       // m half (k >= 512)
    bf16x8 a = *(const bf16x8*)(pa_m + ki*32);
    #pragma unroll
    for (int n = 0; n < 4; ++n){
      bf16x8 bb = *(const bf16x8*)(pb + 512 + (long)n*16*1024 + ki*32);
      accs[n] = __builtin_amdgcn_mfma_f32_16x16x32_bf16(a, bb, accs[n], 0,0,0);
    }
  }
  #pragma unroll
  for (int n = 0; n < 4; ++n){
    int o = wgN*64 + n*16 + ln;
    float bias = fcb[o];
    #pragma unroll
    for (int rr = 0; rr < 4; ++rr){
      int row = wgM*64 + wave*16 + quad*4 + rr;
      out[(long)row*512 + o] = accs[n][rr] + bias;
    }
  }
}

extern "C" void kernel_launch(void* const* d_in, const int* in_sizes, int n_in,
                              void* d_out, int out_size, void* d_ws, size_t ws_size,
                              hipStream_t stream){
  (void)in_sizes; (void)n_in; (void)out_size; (void)ws_size;
  const float* x    = (const float*)d_in[0];
  const float* h0   = (const float*)d_in[1];
  const float* c0   = (const float*)d_in[2];
  const float* mem0 = (const float*)d_in[3];
  const float* wih  = (const float*)d_in[4];
  const float* whh  = (const float*)d_in[5];
  const float* bih  = (const float*)d_in[6];
  const float* bhh  = (const float*)d_in[7];
  const float* wt   = (const float*)d_in[8];
  const float* fcw  = (const float*)d_in[9];
  const float* fcb  = (const float*)d_in[10];
  float* out = (float*)d_out;
  char* ws = (char*)d_ws;

  unsigned short* x0   = (unsigned short*)(ws + X0_OFF);
  unsigned short* x1   = (unsigned short*)(ws + X1_OFF);
  unsigned short* wi0  = (unsigned short*)(ws + WI0_OFF);
  unsigned short* wi1  = (unsigned short*)(ws + WI1_OFF);
  unsigned short* hh   = (unsigned short*)(ws + HH_OFF);
  unsigned short* hmf  = (unsigned short*)(ws + HMF_OFF);
  unsigned short* mseq = (unsigned short*)(ws + MSEQ_OFF);
  unsigned short* fcwb = (unsigned short*)(ws + FCW_OFF);
  float*          s2p  = (float*)(ws + S2P_OFF);
  unsigned*       bar  = (unsigned*)(ws + BAR_OFF);
  unsigned*       bar2 = (unsigned*)(ws + BAR2_OFF);   // reuses wi0 (dead after xgemm)
  float*          gx   = (float*)(ws + GX_OFF);

  phase0<<<32768, 256, 0, stream>>>(x, h0, mem0, fcw, wih,
                                    x0, x1, wi0, wi1,
                                    hh, hmf, fcwb, out + MEM_OFF, bar);
  xgemm<<<dim3(256, 32), 256, 0, stream>>>(x0, x1, wi0, wi1, bih, bhh, gx);
  recurrent<<<NWG, 320, 0, stream>>>(hh, hmf, mseq, s2p, bar, bar2, out,
                                     gx, whh, wt, c0);
  outgemm<<<dim3(256, 8), 256, 0, stream>>>(hh, mseq, fcwb, fcb, out);
}